// Round 12
// baseline (215.469 us; speedup 1.0000x reference)
//
#include <hip/hip_runtime.h>

// Problem constants
#define NH   32      // query heads
#define NKV  8       // kv heads
#define LQ   2048    // query length
#define SK   2048    // key length
#define DH   128     // head dim
#define BM   256     // q rows per block (4 waves x 64 q)
#define BN   64      // s columns per iteration
#define NT   (SK / BN)   // 32 k-tiles
#define VSTRIDE 72   // prepass transpose LDS stride (shorts)

typedef __attribute__((ext_vector_type(8)))  short bf8;
typedef __attribute__((ext_vector_type(16))) float f16v;
typedef __attribute__((ext_vector_type(4)))  unsigned int u32x4;

#define CL2E 0.12754308753f   // (1/sqrt(128)) * log2(e)

#if __has_builtin(__builtin_amdgcn_exp2f)
#define EXP2F(x) __builtin_amdgcn_exp2f(x)
#else
#define EXP2F(x) exp2f(x)
#endif

// fp32 -> bf16 round-to-nearest-even (finite inputs)
__device__ __forceinline__ unsigned short f2bf(float f) {
    unsigned int u = __builtin_bit_cast(unsigned int, f);
    u = (u + 0x7FFFu + ((u >> 16) & 1u)) >> 16;
    return (unsigned short)u;
}

__device__ __forceinline__ unsigned int cvtpk_bf16(float lo, float hi) {
    unsigned int r;
    asm("v_cvt_pk_bf16_f32 %0, %1, %2" : "=v"(r) : "v"(lo), "v"(hi));
    return r;
}

__device__ __forceinline__ float bflo(unsigned int u) {
    return __builtin_bit_cast(float, u << 16);
}
__device__ __forceinline__ float bfhi(unsigned int u) {
    return __builtin_bit_cast(float, u & 0xFFFF0000u);
}

// offset argument must be a LITERAL 0; fold offsets into both pointers.
#define GLOAD_LDS16(g, l)                                                      \
    __builtin_amdgcn_global_load_lds(                                          \
        (const __attribute__((address_space(1))) void*)(g),                    \
        (__attribute__((address_space(3))) void*)(l), 16, 0, 0)

// ---------------- fused pre-pass: K convert | V transpose | M convert ----------------
// (verified R6/R8/R11)  K: Kb[kv][s][p] 16B chunks, p holds d-chunk c = p ^ (s&15).
// V: VTb [kv][tile t][d][p] 16B chunks, p holds s-chunk c = p ^ (d&7); 16KB tiles.
// M: bf16 pre-scaled by scale*log2e, column-permuted per 64-tile.
__global__ __launch_bounds__(256) void prep_kernel(
    const float* __restrict__ K, unsigned short* __restrict__ Kb,
    const float* __restrict__ V, unsigned short* __restrict__ VTb,
    const float* __restrict__ M, unsigned short* __restrict__ Mb)
{
    __shared__ __align__(16) unsigned short Vl[DH * VSTRIDE];
    const int tid = threadIdx.x;
    const int bid = blockIdx.x;

    if (bid < 1024) {
        // ---- convert K ----
        unsigned int cid = bid * 256 + tid;     // one 16B chunk per thread
        unsigned int p   = cid & 15;
        unsigned int row = cid >> 4;            // kv*2048 + s
        unsigned int s   = row & (SK - 1);
        unsigned int c   = p ^ (s & 15);
        const float* src = K + (size_t)row * DH + c * 8;
        float4 a = *(const float4*)(src);
        float4 b = *(const float4*)(src + 4);
        bf8 o;
        o[0] = (short)f2bf(a.x); o[1] = (short)f2bf(a.y);
        o[2] = (short)f2bf(a.z); o[3] = (short)f2bf(a.w);
        o[4] = (short)f2bf(b.x); o[5] = (short)f2bf(b.y);
        o[6] = (short)f2bf(b.z); o[7] = (short)f2bf(b.w);
        *(bf8*)(Kb + (size_t)row * DH + p * 8) = o;
    } else if (bid < 1280) {
        // ---- transpose V ----
        const int vb = bid - 1024;
        const int kv = vb >> 5;                 // 32 s-tiles per kv head
        const int t  = vb & 31;
        const int s0 = t * 64;
        const float* Vh = V + (size_t)kv * SK * DH;
        #pragma unroll
        for (int i = 0; i < 8; ++i) {
            int idx = tid * 4 + i * 1024;
            int s = idx >> 7, d = idx & 127;
            const float4 v4 = *(const float4*)(Vh + (size_t)(s0 + s) * DH + d);
            Vl[(d + 0) * VSTRIDE + s] = f2bf(v4.x);
            Vl[(d + 1) * VSTRIDE + s] = f2bf(v4.y);
            Vl[(d + 2) * VSTRIDE + s] = f2bf(v4.z);
            Vl[(d + 3) * VSTRIDE + s] = f2bf(v4.w);
        }
        __syncthreads();
        unsigned short* out = VTb + (size_t)(kv * 32 + t) * (DH * 64);
        #pragma unroll
        for (int i = 0; i < 4; ++i) {
            int c = tid + i * 256;              // 1024 chunks of 8 shorts
            int d = c >> 3, p = c & 7;
            int sc = (p ^ (d & 7)) * 8;
            *(bf8*)(out + d * 64 + p * 8) = *(const bf8*)(Vl + d * VSTRIDE + sc);
        }
    } else {
        // ---- convert M ----
        unsigned int cid = (bid - 1280) * 256 + tid;  // one 8-short output chunk
        unsigned int row = cid >> 8;                  // 256 chunks per row
        unsigned int l   = (cid & 255) * 8;           // permuted col index
        unsigned int T   = l & ~63u;
        unsigned int loc = l & 63;
        unsigned int mt = loc >> 5, w = loc & 31;
        unsigned int hh = w >> 4, g0 = (w >> 2) & 3;  // w in {0,8,16,24} -> g0 in {0,2}
        const float* src = M + (size_t)row * SK + T + mt * 32 + hh * 4;
        float4 a = *(const float4*)(src + g0 * 8);
        float4 b = *(const float4*)(src + (g0 + 1) * 8);
        bf8 o;
        o[0] = (short)f2bf(a.x * CL2E); o[1] = (short)f2bf(a.y * CL2E);
        o[2] = (short)f2bf(a.z * CL2E); o[3] = (short)f2bf(a.w * CL2E);
        o[4] = (short)f2bf(b.x * CL2E); o[5] = (short)f2bf(b.y * CL2E);
        o[6] = (short)f2bf(b.z * CL2E); o[7] = (short)f2bf(b.w * CL2E);
        *(bf8*)(Mb + (size_t)row * SK + l) = o;
    }
}

// ---------------- main fused attention ----------------
// R12: 64 q PER WAVE (BM=256, 4 waves, grid 256 = 1 block/CU), __launch_bounds__(256,1)
// -> up to 512 unified regs/wave (no spill through ~450, m08/m24). Mechanism:
//   (a) every aK/aV LDS read feeds TWO MFMAs (qt0,qt1) -> LDS reads/CU halve
//       (256->128 KB per 256-q round; LDS was ~1/3 of the wall);
//   (b) QK has 2 independent accumulator chains per mt (s_qt0, s_qt1) -> 2x chain
//       ILP on the 32-clk matrix pipe; PV has 8 chains.
// All verified R11 machinery retained: swizzled layouts, permlane P-pack, fmaf
// softmax, __syncthreads() double-buffer (1 barrier/iter), prep kernel.
__global__ __launch_bounds__(256, 1) void fattn_kernel(
    const float* __restrict__ Q, const unsigned short* __restrict__ Kb,
    const unsigned short* __restrict__ VTb, const unsigned short* __restrict__ Mb,
    float* __restrict__ O)
{
    __shared__ __align__(1024) unsigned char smem[65536];
    unsigned char* KB = smem;               // 2 x 16KB K tiles [s=64][256B swz]
    unsigned char* VB = smem + 32768;       // 2 x 16KB V tiles [d=128][128B swz]

    const int tid  = threadIdx.x;
    const int wave = tid >> 6;              // 64-q group index
    const int lane = tid & 63;
    const int l32  = lane & 31;
    const int hh   = lane >> 5;

    // XCD swizzle: 32 consecutive logical blocks (= 4 q-heads = 1 kv head) per XCD
    const int bx = ((int)blockIdx.x & 7) * 32 + ((int)blockIdx.x >> 3);
    const int h  = bx >> 3;                 // 8 L-tiles per head
    const int lt = bx & 7;
    const int q0 = lt * BM;
    const int kv = h >> 2;

    const float* Qh = Q + (size_t)h * LQ * DH;
    const unsigned char* Kg = (const unsigned char*)(Kb  + (size_t)kv * SK * DH);
    const unsigned char* Vg = (const unsigned char*)(VTb + (size_t)kv * SK * DH);

    const int qrow0 = q0 + wave * 64 + l32;       // qt0 row; qt1 = +32
    const unsigned short* Mq0 = Mb + (size_t)qrow0 * SK + hh * 16;
    const unsigned short* Mq1 = Mq0 + (size_t)32 * SK;

    // ---- Q preload as B-fragments per q-tile: n=q, k=d = ks*16 + hh*8 + j ----
    bf8 bQ[2][8];
    #pragma unroll
    for (int qt = 0; qt < 2; ++qt) {
        const float* qp = Qh + (size_t)(qrow0 + qt * 32) * DH + hh * 8;
        #pragma unroll
        for (int ks = 0; ks < 8; ++ks) {
            float4 a = *(const float4*)(qp + ks * 16);
            float4 b = *(const float4*)(qp + ks * 16 + 4);
            bf8 o;
            o[0] = (short)f2bf(a.x); o[1] = (short)f2bf(a.y);
            o[2] = (short)f2bf(a.z); o[3] = (short)f2bf(a.w);
            o[4] = (short)f2bf(b.x); o[5] = (short)f2bf(b.y);
            o[6] = (short)f2bf(b.z); o[7] = (short)f2bf(b.w);
            bQ[qt][ks] = o;
        }
    }

    // LDS read byte-offset bases; per-read addr = base ^ (ks<<5) (bits disjoint)
    const int krow0 = l32 * 256 + ((hh * 16) ^ ((l32 & 15) << 4));   // + mt*8192
    const int vrowz = l32 * 128 + ((hh * 16) ^ ((l32 & 7) << 4));    // + dt*4096

    const int stoff = wave * 4096 + lane * 16;   // staging: 4KB K + 4KB V per wave

    f16v accO[4][2];   // [dt][qt] O^T tiles; col=q, row=d
    #pragma unroll
    for (int dt = 0; dt < 4; ++dt)
        #pragma unroll
        for (int qt = 0; qt < 2; ++qt)
            #pragma unroll
            for (int r = 0; r < 16; ++r) accO[dt][qt][r] = 0.f;
    float lp0 = 0.f, lp1 = 0.f;

    // ---- prologue: stage tile 0 into buffer 0 ----
    #pragma unroll
    for (int c = 0; c < 4; ++c) GLOAD_LDS16(Kg + stoff + c * 1024, KB + stoff + c * 1024);
    #pragma unroll
    for (int c = 0; c < 4; ++c) GLOAD_LDS16(Vg + stoff + c * 1024, VB + stoff + c * 1024);

    for (int t = 0; t < NT; ++t) {
        const int cur = t & 1;
        __syncthreads();   // staging issued last iter complete; prev reads of buf^1 done

        // ---- mask loads for tile t: [qt][mt] 2 x b128 each ----
        const unsigned short* mp0 = Mq0 + t * 64;
        const unsigned short* mp1 = Mq1 + t * 64;
        u32x4 mA00 = *(const u32x4*)(mp0);        // qt0 mt0
        u32x4 mB00 = *(const u32x4*)(mp0 + 8);
        u32x4 mA01 = *(const u32x4*)(mp0 + 32);   // qt0 mt1
        u32x4 mB01 = *(const u32x4*)(mp0 + 40);
        u32x4 mA10 = *(const u32x4*)(mp1);        // qt1 mt0
        u32x4 mB10 = *(const u32x4*)(mp1 + 8);
        u32x4 mA11 = *(const u32x4*)(mp1 + 32);   // qt1 mt1
        u32x4 mB11 = *(const u32x4*)(mp1 + 40);

        // ---- stage tile t+1 into buf^1 (wrap keeps bookkeeping uniform) ----
        {
            const int tn = (t + 1) & (NT - 1);
            const unsigned char* ksrc = Kg + (size_t)tn * 16384 + stoff;
            const unsigned char* vsrc = Vg + (size_t)tn * 16384 + stoff;
            unsigned char* kdst = KB + (cur ^ 1) * 16384 + stoff;
            unsigned char* vdst = VB + (cur ^ 1) * 16384 + stoff;
            #pragma unroll
            for (int c = 0; c < 4; ++c) GLOAD_LDS16(ksrc + c * 1024, kdst + c * 1024);
            #pragma unroll
            for (int c = 0; c < 4; ++c) GLOAD_LDS16(vsrc + c * 1024, vdst + c * 1024);
        }
        __builtin_amdgcn_sched_barrier(0);

        const unsigned char* kb = KB + cur * 16384;
        const unsigned char* vb = VB + cur * 16384;

        // ---- QK mt0: one aK read feeds BOTH q-tiles (2 independent chains) ----
        f16v s0a, s0b;
        #pragma unroll
        for (int r = 0; r < 16; ++r) { s0a[r] = 0.f; s0b[r] = 0.f; }
        __builtin_amdgcn_s_setprio(1);
        #pragma unroll
        for (int ks = 0; ks < 8; ++ks) {
            bf8 aK = *(const bf8*)(kb + (krow0 ^ (ks << 5)));
            s0a = __builtin_amdgcn_mfma_f32_32x32x16_bf16(aK, bQ[0][ks], s0a, 0, 0, 0);
            s0b = __builtin_amdgcn_mfma_f32_32x32x16_bf16(aK, bQ[1][ks], s0b, 0, 0, 0);
        }
        __builtin_amdgcn_s_setprio(0);

        // ---- softmax mt0 (both qt) ----
        unsigned int pk00[8], pk10[8];   // [qt? first digit=qt][mt in name: *0 = mt0]
        #pragma unroll
        for (int g = 0; g < 4; ++g) {
            unsigned int u0 = (g < 2) ? mA00[g * 2 + 0] : mB00[(g - 2) * 2 + 0];
            unsigned int u1 = (g < 2) ? mA00[g * 2 + 1] : mB00[(g - 2) * 2 + 1];
            float e0 = EXP2F(fmaf(s0a[g*4+0], CL2E, bflo(u0)));
            float e1 = EXP2F(fmaf(s0a[g*4+1], CL2E, bfhi(u0)));
            float e2 = EXP2F(fmaf(s0a[g*4+2], CL2E, bflo(u1)));
            float e3 = EXP2F(fmaf(s0a[g*4+3], CL2E, bfhi(u1)));
            lp0 += (e0 + e1) + (e2 + e3);
            pk00[g*2+0] = cvtpk_bf16(e0, e1);
            pk00[g*2+1] = cvtpk_bf16(e2, e3);
        }
        #pragma unroll
        for (int g = 0; g < 4; ++g) {
            unsigned int u0 = (g < 2) ? mA10[g * 2 + 0] : mB10[(g - 2) * 2 + 0];
            unsigned int u1 = (g < 2) ? mA10[g * 2 + 1] : mB10[(g - 2) * 2 + 1];
            float e0 = EXP2F(fmaf(s0b[g*4+0], CL2E, bflo(u0)));
            float e1 = EXP2F(fmaf(s0b[g*4+1], CL2E, bfhi(u0)));
            float e2 = EXP2F(fmaf(s0b[g*4+2], CL2E, bflo(u1)));
            float e3 = EXP2F(fmaf(s0b[g*4+3], CL2E, bfhi(u1)));
            lp1 += (e0 + e1) + (e2 + e3);
            pk10[g*2+0] = cvtpk_bf16(e0, e1);
            pk10[g*2+1] = cvtpk_bf16(e2, e3);
        }

        // ---- QK mt1 ----
        f16v s1a, s1b;
        #pragma unroll
        for (int r = 0; r < 16; ++r) { s1a[r] = 0.f; s1b[r] = 0.f; }
        __builtin_amdgcn_s_setprio(1);
        #pragma unroll
        for (int ks = 0; ks < 8; ++ks) {
            bf8 aK = *(const bf8*)(kb + 8192 + (krow0 ^ (ks << 5)));
            s1a = __builtin_amdgcn_mfma_f32_32x32x16_bf16(aK, bQ[0][ks], s1a, 0, 0, 0);
            s1b = __builtin_amdgcn_mfma_f32_32x32x16_bf16(aK, bQ[1][ks], s1b, 0, 0, 0);
        }
        __builtin_amdgcn_s_setprio(0);

        // ---- softmax mt1 (both qt) ----
        unsigned int pk01[8], pk11[8];
        #pragma unroll
        for (int g = 0; g < 4; ++g) {
            unsigned int u0 = (g < 2) ? mA01[g * 2 + 0] : mB01[(g - 2) * 2 + 0];
            unsigned int u1 = (g < 2) ? mA01[g * 2 + 1] : mB01[(g - 2) * 2 + 1];
            float e0 = EXP2F(fmaf(s1a[g*4+0], CL2E, bflo(u0)));
            float e1 = EXP2F(fmaf(s1a[g*4+1], CL2E, bfhi(u0)));
            float e2 = EXP2F(fmaf(s1a[g*4+2], CL2E, bflo(u1)));
            float e3 = EXP2F(fmaf(s1a[g*4+3], CL2E, bfhi(u1)));
            lp0 += (e0 + e1) + (e2 + e3);
            pk01[g*2+0] = cvtpk_bf16(e0, e1);
            pk01[g*2+1] = cvtpk_bf16(e2, e3);
        }
        #pragma unroll
        for (int g = 0; g < 4; ++g) {
            unsigned int u0 = (g < 2) ? mA11[g * 2 + 0] : mB11[(g - 2) * 2 + 0];
            unsigned int u1 = (g < 2) ? mA11[g * 2 + 1] : mB11[(g - 2) * 2 + 1];
            float e0 = EXP2F(fmaf(s1b[g*4+0], CL2E, bflo(u0)));
            float e1 = EXP2F(fmaf(s1b[g*4+1], CL2E, bfhi(u0)));
            float e2 = EXP2F(fmaf(s1b[g*4+2], CL2E, bflo(u1)));
            float e3 = EXP2F(fmaf(s1b[g*4+3], CL2E, bfhi(u1)));
            lp1 += (e0 + e1) + (e2 + e3);
            pk11[g*2+0] = cvtpk_bf16(e0, e1);
            pk11[g*2+1] = cvtpk_bf16(e2, e3);
        }

        // ---- bP per q-tile via v_permlane32_swap_b32 (verified R4/R5 pattern):
        // ks<2 from mt0 words, ks>=2 from mt1 words; kk = ks&1.
        bf8 bP0[4], bP1[4];
        #pragma unroll
        for (int ks = 0; ks < 4; ++ks) {
            const int kk = ks & 1;
            {
                unsigned int* pk = (ks >> 1) ? pk01 : pk00;
                unsigned int a0 = pk[kk*4+0], b0 = pk[kk*4+2];
                unsigned int a1 = pk[kk*4+1], b1 = pk[kk*4+3];
                asm volatile("v_permlane32_swap_b32 %0, %1" : "+v"(a0), "+v"(b0));
                asm volatile("v_permlane32_swap_b32 %0, %1" : "+v"(a1), "+v"(b1));
                u32x4 w; w[0] = a0; w[1] = a1; w[2] = b0; w[3] = b1;
                bP0[ks] = __builtin_bit_cast(bf8, w);
            }
            {
                unsigned int* pk = (ks >> 1) ? pk11 : pk10;
                unsigned int a0 = pk[kk*4+0], b0 = pk[kk*4+2];
                unsigned int a1 = pk[kk*4+1], b1 = pk[kk*4+3];
                asm volatile("v_permlane32_swap_b32 %0, %1" : "+v"(a0), "+v"(b0));
                asm volatile("v_permlane32_swap_b32 %0, %1" : "+v"(a1), "+v"(b1));
                u32x4 w; w[0] = a0; w[1] = a1; w[2] = b0; w[3] = b1;
                bP1[ks] = __builtin_bit_cast(bf8, w);
            }
        }

        // ---- PV: one aV read feeds BOTH q-tiles; 8 independent chains ----
        __builtin_amdgcn_s_setprio(1);
        #pragma unroll
        for (int dt = 0; dt < 4; ++dt) {
            #pragma unroll
            for (int ks = 0; ks < 4; ++ks) {
                bf8 aV = *(const bf8*)(vb + dt * 4096 + (vrowz ^ (ks << 5)));
                accO[dt][0] = __builtin_amdgcn_mfma_f32_32x32x16_bf16(aV, bP0[ks], accO[dt][0], 0, 0, 0);
                accO[dt][1] = __builtin_amdgcn_mfma_f32_32x32x16_bf16(aV, bP1[ks], accO[dt][1], 0, 0, 0);
            }
        }
        __builtin_amdgcn_s_setprio(0);
    }

    // ---- epilogue: waves own disjoint O rows -> no reduction ----
    asm volatile("s_waitcnt vmcnt(0)" ::: "memory");   // drain wrap-stage
    float l0 = lp0 + __shfl_xor(lp0, 32);
    float l1 = lp1 + __shfl_xor(lp1, 32);
    const float inv0 = 1.0f / l0;
    const float inv1 = 1.0f / l1;
    float* Op0 = O + (size_t)h * LQ * DH + (size_t)qrow0 * DH;
    #pragma unroll
    for (int qt = 0; qt < 2; ++qt) {
        const float inv = qt ? inv1 : inv0;
        float* Op = Op0 + (size_t)qt * 32 * DH;
        #pragma unroll
        for (int dt = 0; dt < 4; ++dt) {
            #pragma unroll
            for (int g = 0; g < 4; ++g) {
                int d = dt * 32 + g * 8 + hh * 4;
                float4 o;
                o.x = accO[dt][qt][g * 4 + 0] * inv;
                o.y = accO[dt][qt][g * 4 + 1] * inv;
                o.z = accO[dt][qt][g * 4 + 2] * inv;
                o.w = accO[dt][qt][g * 4 + 3] * inv;
                *(float4*)(Op + d) = o;
            }
        }
    }
}

extern "C" void kernel_launch(void* const* d_in, const int* in_sizes, int n_in,
                              void* d_out, int out_size, void* d_ws, size_t ws_size,
                              hipStream_t stream) {
    const float* Q = (const float*)d_in[0];   // [1,32,2048,128]
    const float* K = (const float*)d_in[1];   // [1,8,2048,128]
    const float* V = (const float*)d_in[2];   // [1,8,2048,128]
    const float* M = (const float*)d_in[3];   // [1,1,2048,2048]
    float* O = (float*)d_out;

    // workspace: Kb bf16 [8*2048*128], VTb bf16 [8*128*2048], Mb bf16 [2048*2048]
    unsigned short* Kb  = (unsigned short*)d_ws;
    unsigned short* VTb = Kb + (size_t)NKV * SK * DH;
    unsigned short* Mb  = VTb + (size_t)NKV * DH * SK;

    // fused pre-pass: 1024 (K) + 256 (V) + 2048 (M) blocks
    prep_kernel<<<dim3(3328), 256, 0, stream>>>(K, Kb, V, VTb, M, Mb);

    dim3 grid(NH * (LQ / BM));                // 32 heads x 8 L-tiles = 256 blocks = 1/CU
    fattn_kernel<<<grid, 256, 0, stream>>>(Q, Kb, VTb, Mb, O);
}

// Round 13
// 183.480 us; speedup vs baseline: 1.1743x; 1.1743x over previous
//
#include <hip/hip_runtime.h>

// Problem constants
#define NH   32      // query heads
#define NKV  8       // kv heads
#define LQ   2048    // query length
#define SK   2048    // key length
#define DH   128     // head dim
#define BM   128     // q rows per block (4 waves x 32 q)
#define BN   64      // s columns per iteration
#define NT   (SK / BN)   // 32 k-tiles
#define VSTRIDE 72   // prepass transpose LDS stride (shorts)

typedef __attribute__((ext_vector_type(8)))  short bf8;
typedef __attribute__((ext_vector_type(16))) float f16v;
typedef __attribute__((ext_vector_type(4)))  unsigned int u32x4;

#define CL2E 0.12754308753f   // (1/sqrt(128)) * log2(e)

#if __has_builtin(__builtin_amdgcn_exp2f)
#define EXP2F(x) __builtin_amdgcn_exp2f(x)
#else
#define EXP2F(x) exp2f(x)
#endif

// fp32 -> bf16 round-to-nearest-even (finite inputs)
__device__ __forceinline__ unsigned short f2bf(float f) {
    unsigned int u = __builtin_bit_cast(unsigned int, f);
    u = (u + 0x7FFFu + ((u >> 16) & 1u)) >> 16;
    return (unsigned short)u;
}

__device__ __forceinline__ unsigned int cvtpk_bf16(float lo, float hi) {
    unsigned int r;
    asm("v_cvt_pk_bf16_f32 %0, %1, %2" : "=v"(r) : "v"(lo), "v"(hi));
    return r;
}

__device__ __forceinline__ float bflo(unsigned int u) {
    return __builtin_bit_cast(float, u << 16);
}
__device__ __forceinline__ float bfhi(unsigned int u) {
    return __builtin_bit_cast(float, u & 0xFFFF0000u);
}

// offset argument must be a LITERAL 0; fold offsets into both pointers.
#define GLOAD_LDS16(g, l)                                                      \
    __builtin_amdgcn_global_load_lds(                                          \
        (const __attribute__((address_space(1))) void*)(g),                    \
        (__attribute__((address_space(3))) void*)(l), 16, 0, 0)

// ---------------- fused pre-pass: K convert | V transpose | M convert ----------------
// (verified R6/R8/R11)  K: Kb[kv][s][p] 16B chunks, p holds d-chunk c = p ^ (s&15).
// V: VTb [kv][tile t][d][p] 16B chunks, p holds s-chunk c = p ^ (d&7); 16KB tiles.
// M: bf16 pre-scaled by scale*log2e, column-permuted per 64-tile.
__global__ __launch_bounds__(256) void prep_kernel(
    const float* __restrict__ K, unsigned short* __restrict__ Kb,
    const float* __restrict__ V, unsigned short* __restrict__ VTb,
    const float* __restrict__ M, unsigned short* __restrict__ Mb)
{
    __shared__ __align__(16) unsigned short Vl[DH * VSTRIDE];
    const int tid = threadIdx.x;
    const int bid = blockIdx.x;

    if (bid < 1024) {
        // ---- convert K ----
        unsigned int cid = bid * 256 + tid;     // one 16B chunk per thread
        unsigned int p   = cid & 15;
        unsigned int row = cid >> 4;            // kv*2048 + s
        unsigned int s   = row & (SK - 1);
        unsigned int c   = p ^ (s & 15);
        const float* src = K + (size_t)row * DH + c * 8;
        float4 a = *(const float4*)(src);
        float4 b = *(const float4*)(src + 4);
        bf8 o;
        o[0] = (short)f2bf(a.x); o[1] = (short)f2bf(a.y);
        o[2] = (short)f2bf(a.z); o[3] = (short)f2bf(a.w);
        o[4] = (short)f2bf(b.x); o[5] = (short)f2bf(b.y);
        o[6] = (short)f2bf(b.z); o[7] = (short)f2bf(b.w);
        *(bf8*)(Kb + (size_t)row * DH + p * 8) = o;
    } else if (bid < 1280) {
        // ---- transpose V ----
        const int vb = bid - 1024;
        const int kv = vb >> 5;                 // 32 s-tiles per kv head
        const int t  = vb & 31;
        const int s0 = t * 64;
        const float* Vh = V + (size_t)kv * SK * DH;
        #pragma unroll
        for (int i = 0; i < 8; ++i) {
            int idx = tid * 4 + i * 1024;
            int s = idx >> 7, d = idx & 127;
            const float4 v4 = *(const float4*)(Vh + (size_t)(s0 + s) * DH + d);
            Vl[(d + 0) * VSTRIDE + s] = f2bf(v4.x);
            Vl[(d + 1) * VSTRIDE + s] = f2bf(v4.y);
            Vl[(d + 2) * VSTRIDE + s] = f2bf(v4.z);
            Vl[(d + 3) * VSTRIDE + s] = f2bf(v4.w);
        }
        __syncthreads();
        unsigned short* out = VTb + (size_t)(kv * 32 + t) * (DH * 64);
        #pragma unroll
        for (int i = 0; i < 4; ++i) {
            int c = tid + i * 256;              // 1024 chunks of 8 shorts
            int d = c >> 3, p = c & 7;
            int sc = (p ^ (d & 7)) * 8;
            *(bf8*)(out + d * 64 + p * 8) = *(const bf8*)(Vl + d * VSTRIDE + sc);
        }
    } else {
        // ---- convert M ----
        unsigned int cid = (bid - 1280) * 256 + tid;  // one 8-short output chunk
        unsigned int row = cid >> 8;                  // 256 chunks per row
        unsigned int l   = (cid & 255) * 8;           // permuted col index
        unsigned int T   = l & ~63u;
        unsigned int loc = l & 63;
        unsigned int mt = loc >> 5, w = loc & 31;
        unsigned int hh = w >> 4, g0 = (w >> 2) & 3;  // w in {0,8,16,24} -> g0 in {0,2}
        const float* src = M + (size_t)row * SK + T + mt * 32 + hh * 4;
        float4 a = *(const float4*)(src + g0 * 8);
        float4 b = *(const float4*)(src + (g0 + 1) * 8);
        bf8 o;
        o[0] = (short)f2bf(a.x * CL2E); o[1] = (short)f2bf(a.y * CL2E);
        o[2] = (short)f2bf(a.z * CL2E); o[3] = (short)f2bf(a.w * CL2E);
        o[4] = (short)f2bf(b.x * CL2E); o[5] = (short)f2bf(b.y * CL2E);
        o[6] = (short)f2bf(b.z * CL2E); o[7] = (short)f2bf(b.w * CL2E);
        *(bf8*)(Mb + (size_t)row * SK + l) = o;
    }
}

// ---------------- main fused attention ----------------
// R11 base (4 waves = 4 q-tiles of 32 rows, cross-iter pipeline, 1 barrier/iter)
// + R13 delta: each QK 8-deep DEPENDENT MFMA chain split into two independent
// 4-deep sub-chains (tL: ks0-3, tH: ks4-7) merged with 16 VALU adds. Halves the
// dep-latency-blocked time on the matrix pipe (8x64 -> 4x64 clk per mt) at a cost
// of +32 transient regs and +64 VALU ops/iter. (R12's 64q/wave ILP attempt
// regressed: 1 wave/SIMD exposes all latency; TLP >= 2/SIMD required.)
#define QKSPLIT(BASE, SNX)                                                     \
    {                                                                          \
      f16v tL, tH;                                                             \
      _Pragma("unroll")                                                        \
      for (int r = 0; r < 16; ++r) { tL[r] = 0.f; tH[r] = 0.f; }               \
      __builtin_amdgcn_s_setprio(1);                                           \
      _Pragma("unroll")                                                        \
      for (int ks = 0; ks < 4; ++ks) {                                         \
        bf8 aKl = *(const bf8*)((BASE) + (krow0 ^ (ks << 5)));                 \
        bf8 aKh = *(const bf8*)((BASE) + (krow0 ^ ((ks + 4) << 5)));           \
        tL = __builtin_amdgcn_mfma_f32_32x32x16_bf16(aKl, bQ[ks], tL, 0, 0, 0);\
        tH = __builtin_amdgcn_mfma_f32_32x32x16_bf16(aKh, bQ[ks + 4], tH, 0, 0, 0);\
      }                                                                        \
      __builtin_amdgcn_s_setprio(0);                                           \
      _Pragma("unroll")                                                        \
      for (int r = 0; r < 16; ++r) SNX[r] = tL[r] + tH[r];                     \
    }

#define BODY(T, CUR, SC0, SC1, SN0, SN1)                                       \
  {                                                                            \
    __syncthreads();                                                           \
    const unsigned short* mp = Mq + (T) * 64;                                  \
    u32x4 mA0 = *(const u32x4*)(mp);                                           \
    u32x4 mB0 = *(const u32x4*)(mp + 8);                                       \
    u32x4 mA1 = *(const u32x4*)(mp + 32);                                      \
    u32x4 mB1 = *(const u32x4*)(mp + 40);                                      \
    {                                                                          \
      const int tv = ((T) + 1) & (NT - 1);                                     \
      const int tk = ((T) + 2) & (NT - 1);                                     \
      const unsigned char* vsrc = Vg + (size_t)tv * 16384 + stoff;             \
      const unsigned char* ksrc = Kg + (size_t)tk * 16384 + stoff;             \
      unsigned char* vdst = VB + ((CUR) ^ 1) * 16384 + stoff;                  \
      unsigned char* kdst = KB + (CUR) * 16384 + stoff;                        \
      _Pragma("unroll")                                                        \
      for (int c = 0; c < 4; ++c) GLOAD_LDS16(vsrc + c * 1024, vdst + c * 1024); \
      _Pragma("unroll")                                                        \
      for (int c = 0; c < 4; ++c) GLOAD_LDS16(ksrc + c * 1024, kdst + c * 1024); \
    }                                                                          \
    __builtin_amdgcn_sched_barrier(0);                                         \
    const unsigned char* kbn = KB + ((CUR) ^ 1) * 16384;                       \
    const unsigned char* vbc = VB + (CUR) * 16384;                             \
    QKSPLIT(kbn, SN0)                                                          \
    unsigned int pk0[8], pk1[8];                                               \
    _Pragma("unroll")                                                          \
    for (int g = 0; g < 4; ++g) {                                              \
      unsigned int u0 = (g < 2) ? mA0[g * 2 + 0] : mB0[(g - 2) * 2 + 0];       \
      unsigned int u1 = (g < 2) ? mA0[g * 2 + 1] : mB0[(g - 2) * 2 + 1];       \
      float e0 = EXP2F(fmaf(SC0[g*4+0], CL2E, bflo(u0)));                      \
      float e1 = EXP2F(fmaf(SC0[g*4+1], CL2E, bfhi(u0)));                      \
      float e2 = EXP2F(fmaf(SC0[g*4+2], CL2E, bflo(u1)));                      \
      float e3 = EXP2F(fmaf(SC0[g*4+3], CL2E, bfhi(u1)));                      \
      lpA += (e0 + e1) + (e2 + e3);                                            \
      pk0[g*2+0] = cvtpk_bf16(e0, e1);                                         \
      pk0[g*2+1] = cvtpk_bf16(e2, e3);                                         \
    }                                                                          \
    QKSPLIT(kbn + 8192, SN1)                                                   \
    _Pragma("unroll")                                                          \
    for (int g = 0; g < 4; ++g) {                                              \
      unsigned int u0 = (g < 2) ? mA1[g * 2 + 0] : mB1[(g - 2) * 2 + 0];       \
      unsigned int u1 = (g < 2) ? mA1[g * 2 + 1] : mB1[(g - 2) * 2 + 1];       \
      float e0 = EXP2F(fmaf(SC1[g*4+0], CL2E, bflo(u0)));                      \
      float e1 = EXP2F(fmaf(SC1[g*4+1], CL2E, bfhi(u0)));                      \
      float e2 = EXP2F(fmaf(SC1[g*4+2], CL2E, bflo(u1)));                      \
      float e3 = EXP2F(fmaf(SC1[g*4+3], CL2E, bfhi(u1)));                      \
      lpB += (e0 + e1) + (e2 + e3);                                            \
      pk1[g*2+0] = cvtpk_bf16(e0, e1);                                         \
      pk1[g*2+1] = cvtpk_bf16(e2, e3);                                         \
    }                                                                          \
    bf8 bP[4];                                                                 \
    _Pragma("unroll")                                                          \
    for (int ks = 0; ks < 4; ++ks) {                                           \
      unsigned int* pk = (ks >> 1) ? pk1 : pk0;                                \
      const int kk = ks & 1;                                                   \
      unsigned int a0 = pk[kk*4+0], b0 = pk[kk*4+2];                           \
      unsigned int a1 = pk[kk*4+1], b1 = pk[kk*4+3];                           \
      asm volatile("v_permlane32_swap_b32 %0, %1" : "+v"(a0), "+v"(b0));       \
      asm volatile("v_permlane32_swap_b32 %0, %1" : "+v"(a1), "+v"(b1));       \
      u32x4 w; w[0] = a0; w[1] = a1; w[2] = b0; w[3] = b1;                     \
      bP[ks] = __builtin_bit_cast(bf8, w);                                     \
    }                                                                          \
    __builtin_amdgcn_s_setprio(1);                                             \
    _Pragma("unroll")                                                          \
    for (int dt = 0; dt < 4; ++dt) {                                           \
      _Pragma("unroll")                                                        \
      for (int ks = 0; ks < 4; ++ks) {                                         \
        bf8 aV = *(const bf8*)(vbc + dt * 4096 + (vrowz ^ (ks << 5)));         \
        accO[dt] = __builtin_amdgcn_mfma_f32_32x32x16_bf16(aV, bP[ks], accO[dt], 0, 0, 0); \
      }                                                                        \
    }                                                                          \
    __builtin_amdgcn_s_setprio(0);                                             \
  }

__global__ __launch_bounds__(256, 2) void fattn_kernel(
    const float* __restrict__ Q, const unsigned short* __restrict__ Kb,
    const unsigned short* __restrict__ VTb, const unsigned short* __restrict__ Mb,
    float* __restrict__ O)
{
    __shared__ __align__(1024) unsigned char smem[65536];
    unsigned char* KB = smem;               // 2 x 16KB K tiles [s=64][256B swz]
    unsigned char* VB = smem + 32768;       // 2 x 16KB V tiles [d=128][128B swz]

    const int tid  = threadIdx.x;
    const int wave = tid >> 6;              // q-tile index
    const int lane = tid & 63;
    const int l32  = lane & 31;
    const int hh   = lane >> 5;

    // XCD swizzle: 64 consecutive logical blocks (= 1 kv head) per XCD
    const int bx = ((int)blockIdx.x & 7) * 64 + ((int)blockIdx.x >> 3);
    const int h  = bx >> 4;
    const int lt = bx & 15;
    const int q0 = lt * BM;
    const int kv = h >> 2;

    const float* Qh = Q + (size_t)h * LQ * DH;
    const unsigned char* Kg = (const unsigned char*)(Kb  + (size_t)kv * SK * DH);
    const unsigned char* Vg = (const unsigned char*)(VTb + (size_t)kv * SK * DH);

    const int qrow = q0 + wave * 32 + l32;
    const unsigned short* Mq = Mb + (size_t)qrow * SK + hh * 16;

    // ---- Q preload as B-fragments (unscaled): n=q, k=d = ks*16 + hh*8 + j ----
    bf8 bQ[8];
    {
        const float* qp = Qh + (size_t)qrow * DH + hh * 8;
        #pragma unroll
        for (int ks = 0; ks < 8; ++ks) {
            float4 a = *(const float4*)(qp + ks * 16);
            float4 b = *(const float4*)(qp + ks * 16 + 4);
            bf8 o;
            o[0] = (short)f2bf(a.x); o[1] = (short)f2bf(a.y);
            o[2] = (short)f2bf(a.z); o[3] = (short)f2bf(a.w);
            o[4] = (short)f2bf(b.x); o[5] = (short)f2bf(b.y);
            o[6] = (short)f2bf(b.z); o[7] = (short)f2bf(b.w);
            bQ[ks] = o;
        }
    }

    // LDS read byte-offset bases; per-read addr = base ^ (ks<<5) (bits disjoint)
    const int krow0 = l32 * 256 + ((hh * 16) ^ ((l32 & 15) << 4));   // + mt*8192
    const int vrowz = l32 * 128 + ((hh * 16) ^ ((l32 & 7) << 4));    // + dt*4096

    const int stoff = wave * 4096 + lane * 16;   // staging: 4KB K + 4KB V per wave

    f16v accO[4];     // O^T tiles over d (4 x 32); col=q, row=d
    #pragma unroll
    for (int dt = 0; dt < 4; ++dt)
        #pragma unroll
        for (int r = 0; r < 16; ++r) accO[dt][r] = 0.f;
    float lpA = 0.f, lpB = 0.f;

    // ---- prologue: K0->KB0, V0->VB0, K1->KB1; sync; then S_0 into sA ----
    #pragma unroll
    for (int c = 0; c < 4; ++c) GLOAD_LDS16(Kg + stoff + c * 1024, KB + stoff + c * 1024);
    #pragma unroll
    for (int c = 0; c < 4; ++c) GLOAD_LDS16(Vg + stoff + c * 1024, VB + stoff + c * 1024);
    #pragma unroll
    for (int c = 0; c < 4; ++c) GLOAD_LDS16(Kg + 16384 + stoff + c * 1024, KB + 16384 + stoff + c * 1024);
    __syncthreads();

    f16v sA0, sA1, sB0, sB1;
    QKSPLIT(KB, sA0)
    QKSPLIT(KB + 8192, sA1)

    // ---- main loop: 2x unrolled to keep S registers statically named ----
    for (int tt = 0; tt < NT; tt += 2) {
        BODY(tt + 0, 0, sA0, sA1, sB0, sB1)
        BODY(tt + 1, 1, sB0, sB1, sA0, sA1)
    }

    // ---- epilogue: waves own disjoint O rows -> no reduction ----
    asm volatile("s_waitcnt vmcnt(0)" ::: "memory");   // drain wrap-stage
    float lpart = lpA + lpB;
    float l = lpart + __shfl_xor(lpart, 32);
    float inv = 1.0f / l;
    float* Op = O + (size_t)h * LQ * DH + (size_t)qrow * DH;
    #pragma unroll
    for (int dt = 0; dt < 4; ++dt) {
        #pragma unroll
        for (int g = 0; g < 4; ++g) {
            int d = dt * 32 + g * 8 + hh * 4;
            float4 o;
            o.x = accO[dt][g * 4 + 0] * inv;
            o.y = accO[dt][g * 4 + 1] * inv;
            o.z = accO[dt][g * 4 + 2] * inv;
            o.w = accO[dt][g * 4 + 3] * inv;
            *(float4*)(Op + d) = o;
        }
    }
}

extern "C" void kernel_launch(void* const* d_in, const int* in_sizes, int n_in,
                              void* d_out, int out_size, void* d_ws, size_t ws_size,
                              hipStream_t stream) {
    const float* Q = (const float*)d_in[0];   // [1,32,2048,128]
    const float* K = (const float*)d_in[1];   // [1,8,2048,128]
    const float* V = (const float*)d_in[2];   // [1,8,2048,128]
    const float* M = (const float*)d_in[3];   // [1,1,2048,2048]
    float* O = (float*)d_out;

    // workspace: Kb bf16 [8*2048*128], VTb bf16 [8*128*2048], Mb bf16 [2048*2048]
    unsigned short* Kb  = (unsigned short*)d_ws;
    unsigned short* VTb = Kb + (size_t)NKV * SK * DH;
    unsigned short* Mb  = VTb + (size_t)NKV * DH * SK;

    // fused pre-pass: 1024 (K) + 256 (V) + 2048 (M) blocks
    prep_kernel<<<dim3(3328), 256, 0, stream>>>(K, Kb, V, VTb, M, Mb);

    dim3 grid(NH * (LQ / BM));                // 32 heads x 16 L-tiles = 512 blocks = 2/CU
    fattn_kernel<<<grid, 256, 0, stream>>>(Q, Kb, VTb, Mb, O);
}